// Round 7
// baseline (392.069 us; speedup 1.0000x reference)
//
#include <hip/hip_runtime.h>
#include <stdint.h>

#define A 15
#define H_ 34
#define W_ 34
#define HW (H_*W_)
#define N (A*HW)            // 17340
#define MAX_CAND 3000
#define TOP_N 300
#define NWORDS 47           // ceil(3000/64)
#define HB 13               // histogram bits
#define HSIZE 8192
#define RB 12               // rank blocks

__constant__ float c_aw[A] = {9.232984f, 16.0f, 27.712813f, 18.465969f, 32.0f, 55.425626f,
                              36.931937f, 64.0f, 110.851252f, 73.863875f, 128.0f, 221.702503f,
                              147.72775f, 256.0f, 443.405007f};
__constant__ float c_ah[A] = {27.72668f, 16.0f, 9.237604f, 55.453359f, 32.0f, 18.475209f,
                              110.906719f, 64.0f, 36.950417f, 221.813438f, 128.0f, 73.900834f,
                              443.626876f, 256.0f, 147.801669f};

// ---------------------------------------------------------------------------
// K1: decode boxes/scores/keys; 13-bit histogram (per-thread global atomics);
// zero kpm. Exact reference op order; __f*_rn blocks FMA contraction.
// ---------------------------------------------------------------------------
__global__ __launch_bounds__(256) void k_boxes(
    const float* __restrict__ cls, const float* __restrict__ pred,
    const int* __restrict__ iminfo,
    float4* __restrict__ boxes, float2* __restrict__ scores,
    unsigned long long* __restrict__ keys,
    int* __restrict__ hist, unsigned long long* __restrict__ kpm)
{
    int m = blockIdx.x * 256 + threadIdx.x;
    if (m >= N) return;
    if (m < NWORDS) kpm[m] = 0ull;

    int a  = m % A;
    int hw = m / A;
    int w  = hw % W_;
    int h  = hw / W_;

    float ow = (float)iminfo[1];
    float oh = (float)iminfo[0];

    float aw = c_aw[a], ah = c_ah[a];
    float xm = __fmul_rn(-0.5f, __fsub_rn(aw, 1.0f));
    float ym = __fmul_rn(-0.5f, __fsub_rn(ah, 1.0f));
    float sxw = (float)(w * 8);
    float syh = (float)(h * 8);
    float x1 = __fadd_rn(sxw, xm);
    float y1 = __fadd_rn(syh, ym);
    float x2 = __fadd_rn(sxw, -xm);
    float y2 = __fadd_rn(syh, -ym);

    float widths  = __fadd_rn(__fsub_rn(x2, x1), 1.0f);
    float heights = __fadd_rn(__fsub_rn(y2, y1), 1.0f);
    float ctr_x = __fadd_rn(x1, __fmul_rn(0.5f, __fsub_rn(widths, 1.0f)));
    float ctr_y = __fadd_rn(y1, __fmul_rn(0.5f, __fsub_rn(heights, 1.0f)));

    const float std0 = 0.12677f,   std1 = 0.095741f, std2 = 0.3173f,    std3 = 0.281042f;
    const float mu0  = 0.000437f,  mu1  = 0.002586f, mu2  = -0.123953f, mu3  = -0.081469f;
    int pb = a * 4 * HW + hw;
    float d0 = __fadd_rn(__fmul_rn(pred[pb + 0 * HW], std0), mu0);
    float d1 = __fadd_rn(__fmul_rn(pred[pb + 1 * HW], std1), mu1);
    float d2 = __fadd_rn(__fmul_rn(pred[pb + 2 * HW], std2), mu2);
    float d3 = __fadd_rn(__fmul_rn(pred[pb + 3 * HW], std3), mu3);

    float pcx = __fadd_rn(__fmul_rn(d0, widths),  ctr_x);
    float pcy = __fadd_rn(__fmul_rn(d1, heights), ctr_y);
    float pw  = __fmul_rn(expf(d2), widths);
    float ph  = __fmul_rn(expf(d3), heights);

    float hpw = __fmul_rn(0.5f, __fsub_rn(pw, 1.0f));
    float hph = __fmul_rn(0.5f, __fsub_rn(ph, 1.0f));
    float bx1 = __fsub_rn(pcx, hpw);
    float by1 = __fsub_rn(pcy, hph);
    float bx2 = __fadd_rn(pcx, hpw);
    float by2 = __fadd_rn(pcy, hph);

    float ow1 = __fsub_rn(ow, 1.0f), oh1 = __fsub_rn(oh, 1.0f);
    bx1 = fminf(fmaxf(bx1, 0.0f), ow1);
    by1 = fminf(fmaxf(by1, 0.0f), oh1);
    bx2 = fminf(fmaxf(bx2, 0.0f), ow1);
    by2 = fminf(fmaxf(by2, 0.0f), oh1);

    float s0 = cls[a * HW + hw];
    float s1 = cls[(A + a) * HW + hw];

    float wsv = __fadd_rn(__fsub_rn(bx2, bx1), 1.0f);
    float hsv = __fadd_rn(__fsub_rn(by2, by1), 1.0f);
    bool keep = (s1 > 0.2f) && ((wsv >= 6.16056f) || (hsv >= 6.16056f));
    float masked = keep ? s1 : -1e30f;

    boxes[m]  = make_float4(bx1, by1, bx2, by2);
    scores[m] = make_float2(s0, s1);

    unsigned int fb = __float_as_uint(masked);
    fb = (fb & 0x80000000u) ? ~fb : (fb | 0x80000000u);
    unsigned long long key = ((unsigned long long)fb << 32) | (unsigned int)(~(unsigned int)m);
    keys[m] = key;
    atomicAdd(&hist[(int)(key >> (64 - HB))], 1);
}

// ---------------------------------------------------------------------------
// K2: one block. Suffix-scan 8192-bucket histogram -> threshold bucket B of
// the 3000th-largest key; compact {bucket >= B} with wave-aggregated atomics.
// ---------------------------------------------------------------------------
__global__ __launch_bounds__(1024) void k_thresh(
    const unsigned long long* __restrict__ keys,
    const int* __restrict__ hist,
    unsigned long long* __restrict__ skeys, int* __restrict__ control)
{
    __shared__ int tsum[1024];
    __shared__ int sB;
    int t = threadIdx.x;

    {
        const int4* h4 = (const int4*)hist;
        int4 va = h4[t * 2], vb = h4[t * 2 + 1];
        tsum[t] = va.x + va.y + va.z + va.w + vb.x + vb.y + vb.z + vb.w;
    }
    __syncthreads();
    for (int d = 1; d < 1024; d <<= 1) {
        int v = (t + d < 1024) ? tsum[t + d] : 0;
        __syncthreads();
        tsum[t] += v;
        __syncthreads();
    }
    int suf_self = tsum[t];
    int suf_next = (t < 1023) ? tsum[t + 1] : 0;
    if (suf_self >= MAX_CAND && suf_next < MAX_CAND) {
        int acc = suf_next, B = t * 8;
        const int* hh = hist + t * 8;
        for (int q = 7; q >= 0; --q) {
            acc += hh[q];
            if (acc >= MAX_CAND) { B = t * 8 + q; break; }
        }
        sB = B;
    }
    __syncthreads();
    const int B = sB;

    int ln = t & 63;
    for (int i0 = 0; i0 < N; i0 += 1024) {
        int i = i0 + t;
        bool pass = false;
        unsigned long long k = 0;
        if (i < N) {
            k = keys[i];
            pass = ((int)(k >> (64 - HB)) >= B);
        }
        unsigned long long bal = __ballot(pass);
        int base = 0;
        if (ln == 0) base = atomicAdd(control, (int)__popcll(bal));
        base = __shfl(base, 0, 64);
        if (pass) {
            int off = __popcll(bal & ((1ull << ln) - 1));
            skeys[base + off] = k;
        }
    }
}

// ---------------------------------------------------------------------------
// K3: rank within subset (== global rank for top-3000) + scatter.
// 12 blocks x 1024: 4 j-slices x 256 i per block; wave-uniform global j-reads
// (8-unrolled, scalar-load friendly); LDS partial-sum; inline scatter.
// Origin index recovered from key low bits (~m).
// ---------------------------------------------------------------------------
__global__ __launch_bounds__(1024) void k_rank(
    const int* __restrict__ control,
    const unsigned long long* __restrict__ skeys,
    const float4* __restrict__ boxes, const float2* __restrict__ scores,
    float4* __restrict__ cboxes, float2* __restrict__ cscores,
    unsigned long long* __restrict__ kpm)
{
    __shared__ int pc[1024];
    const int S = control[0];
    const int tid = threadIdx.x;
    const int js = tid >> 8;         // 4 j-slices
    const int il = tid & 255;

    for (int ib = blockIdx.x; ib * 256 < S; ib += RB) {
        int i = ib * 256 + il;
        unsigned long long mk = (i < S) ? skeys[i] : ~0ull;
        int jlen = (S + 3) >> 2;
        int j0 = js * jlen;
        int j1 = min(j0 + jlen, S);
        int cnt = 0;
        int j = j0;
        for (; j + 8 <= j1; j += 8) {
            #pragma unroll
            for (int u = 0; u < 8; ++u) cnt += (skeys[j + u] > mk) ? 1 : 0;
        }
        for (; j < j1; ++j) cnt += (skeys[j] > mk) ? 1 : 0;
        pc[js * 256 + il] = cnt;
        __syncthreads();

        if (tid < 256) {
            int i2 = ib * 256 + tid;
            if (i2 < S) {
                int rank = pc[tid] + pc[256 + tid] + pc[512 + tid] + pc[768 + tid];
                if (rank < MAX_CAND) {
                    unsigned long long kk = skeys[i2];
                    int orig = (int)(~(unsigned int)kk);   // low 32 bits = ~m
                    cboxes[rank]  = boxes[orig];
                    cscores[rank] = scores[orig];
                    unsigned int fb = (unsigned int)(kk >> 32);
                    float masked = (fb & 0x80000000u) ? __uint_as_float(fb & 0x7fffffffu)
                                                      : __uint_as_float(~fb);
                    if (masked > (-1e30f * 0.5f))
                        atomicOr(&kpm[rank >> 6], 1ull << (rank & 63));
                }
            }
        }
        __syncthreads();
    }
}

// ---------------------------------------------------------------------------
// K4: fused IoU + chunked greedy NMS, single block. All 3000 boxes + areas
// staged in LDS; IoU computed on demand (no sup matrix). Early exit once
// kept>=300; ffs-skip serial resolve; per-wave fold over later words.
// ---------------------------------------------------------------------------
__device__ __forceinline__ bool iou_gt(
    float4 bi, float ai, float4 bj, float aj)
{
    float iw = fmaxf(__fsub_rn(fminf(bi.z, bj.z), fmaxf(bi.x, bj.x)), 0.0f);
    float ih = fmaxf(__fsub_rn(fminf(bi.w, bj.w), fmaxf(bi.y, bj.y)), 0.0f);
    float inter = __fmul_rn(iw, ih);
    float denom = fmaxf(__fsub_rn(__fadd_rn(ai, aj), inter), 1e-12f);
    return (inter / denom) > 0.7f;
}

__global__ __launch_bounds__(1024) void k_nms(
    const unsigned long long* __restrict__ kpm,
    const float4* __restrict__ cboxes, const float2* __restrict__ cscores,
    float* __restrict__ out)
{
    __shared__ float4 s_bx[MAX_CAND];              // 48 KB
    __shared__ float  s_ar[MAX_CAND];              // 12 KB
    __shared__ unsigned long long s_kp[NWORDS];
    __shared__ unsigned long long s_intra[64];
    __shared__ int s_sel[TOP_N];
    __shared__ int s_misc[2];

    const int tid  = threadIdx.x;
    const int lane = tid & 63;
    const int wave = tid >> 6;

    for (int t = tid; t < TOP_N * 7; t += 1024) out[t] = 0.0f;
    for (int t = tid; t < TOP_N; t += 1024) s_sel[t] = -1;
    if (tid < NWORDS) s_kp[tid] = kpm[tid];
    for (int k = tid; k < MAX_CAND; k += 1024) {
        float4 b = cboxes[k];
        s_bx[k] = b;
        s_ar[k] = __fmul_rn(__fsub_rn(b.z, b.x), __fsub_rn(b.w, b.y));
    }
    __syncthreads();

    int kept_total = 0;   // maintained by wave 0 (uniform there)
    for (int w = 0; w < NWORDS; ++w) {
        // ---- A: all 16 waves compute intra words for the 64 rows of word w
        {
            int jc = w * 64 + lane;
            bool jv = (jc < MAX_CAND);
            int jcc = jv ? jc : (MAX_CAND - 1);
            float4 bj = s_bx[jcc];
            float  aj = s_ar[jcc];
            #pragma unroll
            for (int u = 0; u < 4; ++u) {
                int rl = wave * 4 + u;
                int r  = w * 64 + rl;
                bool vi = (r < MAX_CAND);
                int rc = vi ? r : (MAX_CAND - 1);
                float4 bi = s_bx[rc];
                float  ai = s_ar[rc];
                bool p = vi && jv && (jc > r) && iou_gt(bi, ai, bj, aj);
                unsigned long long msk = __ballot(p);
                if (lane == 0) s_intra[rl] = msk;
            }
        }
        __syncthreads();

        // ---- B: wave 0 serial resolve (ffs-skip over nonzero survivor rows)
        if (wave == 0) {
            unsigned long long myintra = s_intra[lane];
            unsigned long long nz = __ballot(myintra != 0ull);
            unsigned long long kw = s_kp[w];
            unsigned long long rem = kw & nz;
            while (rem) {
                int b = __ffsll((long long)rem) - 1;
                rem &= rem - 1;
                if ((kw >> b) & 1ull) {
                    unsigned long long row = __shfl(myintra, b, 64);
                    kw  &= ~row;
                    rem &= ~row;
                }
            }
            if (lane == 0) {
                s_kp[w] = kw;
            }
            kept_total += __popcll(kw);
            bool stop = (kept_total >= TOP_N) || (w == NWORDS - 1);
            if (lane == 0) s_misc[0] = stop ? 1 : 0;
        }
        __syncthreads();
        if (s_misc[0]) break;

        // ---- C: fold kept rows of word w into later words (1 wave per word)
        {
            unsigned long long kwf = s_kp[w];
            if (kwf) {
                for (int u = w + 1 + wave; u < NWORDS; u += 16) {
                    int jc = u * 64 + lane;
                    bool jv = (jc < MAX_CAND);
                    int jcc = jv ? jc : (MAX_CAND - 1);
                    float4 bj = s_bx[jcc];
                    float  aj = s_ar[jcc];
                    bool any = false;
                    unsigned long long t2 = kwf;
                    while (t2) {
                        int b = __ffsll((long long)t2) - 1;
                        t2 &= t2 - 1;
                        int r = w * 64 + b;
                        float4 bi = s_bx[r];
                        float  ai = s_ar[r];
                        any |= iou_gt(bi, ai, bj, aj);   // jc > r guaranteed (u > w)
                    }
                    unsigned long long msk = __ballot(any && jv);
                    if (lane == 0) s_kp[u] &= ~msk;
                }
            }
        }
        __syncthreads();
    }

    // ---- selection + output
    if (wave == 0) {
        unsigned long long kw = (lane < NWORDS) ? s_kp[lane] : 0ull;
        int cnt = __popcll(kw);
        int pre = cnt;
        for (int d = 1; d < 64; d <<= 1) {
            int o = __shfl_up(pre, d, 64);
            if (lane >= d) pre += o;
        }
        int prefix = pre - cnt;
        while (kw && prefix < TOP_N) {
            int b = __ffsll((long long)kw) - 1;
            kw &= kw - 1;
            s_sel[prefix] = lane * 64 + b;
            prefix++;
        }
    }
    __syncthreads();

    if (tid < TOP_N) {
        int j = s_sel[tid];
        if (j >= 0) {
            float4 bx = s_bx[j];
            float2 sc = cscores[j];
            out[tid * 5 + 0] = 0.0f;
            out[tid * 5 + 1] = bx.x;
            out[tid * 5 + 2] = bx.y;
            out[tid * 5 + 3] = bx.z;
            out[tid * 5 + 4] = bx.w;
            out[TOP_N * 5 + tid * 2 + 0] = sc.x;
            out[TOP_N * 5 + tid * 2 + 1] = sc.y;
        }
    }
}

// ---------------------------------------------------------------------------
extern "C" void kernel_launch(void* const* d_in, const int* in_sizes, int n_in,
                              void* d_out, int out_size, void* d_ws, size_t ws_size,
                              hipStream_t stream) {
    const float* cls    = (const float*)d_in[0];
    const float* pred   = (const float*)d_in[1];
    const int*   iminfo = (const int*)d_in[2];
    float* out = (float*)d_out;

    char* p = (char*)d_ws;
    auto alloc = [&](size_t bytes) -> char* {
        char* q = p;
        p += (bytes + 255) & ~(size_t)255;
        return q;
    };
    int* hist    = (int*)alloc((size_t)HSIZE * 4);   // 32768 B
    int* control = (int*)alloc(256);                  // contiguous after hist
    float4* boxes  = (float4*)alloc((size_t)N * sizeof(float4));
    float2* scores = (float2*)alloc((size_t)N * sizeof(float2));
    unsigned long long* keys  = (unsigned long long*)alloc((size_t)N * 8);
    unsigned long long* skeys = (unsigned long long*)alloc((size_t)N * 8);
    float4* cboxes  = (float4*)alloc((size_t)MAX_CAND * sizeof(float4));
    float2* cscores = (float2*)alloc((size_t)MAX_CAND * sizeof(float2));
    unsigned long long* kpm = (unsigned long long*)alloc((size_t)NWORDS * 8);

    hipMemsetAsync(hist, 0, (size_t)HSIZE * 4 + 256, stream);

    int nb = (N + 255) / 256;  // 68
    k_boxes <<<nb, 256, 0, stream>>>(cls, pred, iminfo, boxes, scores, keys, hist, kpm);
    k_thresh<<<1, 1024, 0, stream>>>(keys, hist, skeys, control);
    k_rank  <<<RB, 1024, 0, stream>>>(control, skeys, boxes, scores, cboxes, cscores, kpm);
    k_nms   <<<1, 1024, 0, stream>>>(kpm, cboxes, cscores, out);
}

// Round 8
// 142.000 us; speedup vs baseline: 2.7610x; 2.7610x over previous
//
#include <hip/hip_runtime.h>
#include <stdint.h>

#define A 15
#define H_ 34
#define W_ 34
#define HW (H_*W_)
#define N (A*HW)            // 17340
#define MAX_CAND 3000
#define TOP_N 300
#define NWORDS 47           // ceil(3000/64)
#define CHUNK_W 3008        // 64 rows * 47 words per chunk
#define NBUCK 8000          // linear score buckets (monotone quantization)
#define ITILE 16            // iou rows per block

__constant__ float c_aw[A] = {9.232984f, 16.0f, 27.712813f, 18.465969f, 32.0f, 55.425626f,
                              36.931937f, 64.0f, 110.851252f, 73.863875f, 128.0f, 221.702503f,
                              147.72775f, 256.0f, 443.405007f};
__constant__ float c_ah[A] = {27.72668f, 16.0f, 9.237604f, 55.453359f, 32.0f, 18.475209f,
                              110.906719f, 64.0f, 36.950417f, 221.813438f, 128.0f, 73.900834f,
                              443.626876f, 256.0f, 147.801669f};

// ---------------------------------------------------------------------------
// K1: decode boxes/scores; key = bucket(13) | score-bits(32) | ~idx(15).
// bucket: 0 for masked(-1e30); else 1+floor(s1*7998) -- monotone in masked,
// ties resolved by exact float bits then by lower-index-first (~idx).
// Exact reference op order; __f*_rn blocks FMA contraction.
// ---------------------------------------------------------------------------
__global__ __launch_bounds__(256) void k_boxes(
    const float* __restrict__ cls, const float* __restrict__ pred,
    const int* __restrict__ iminfo,
    float4* __restrict__ boxes, float2* __restrict__ scores,
    unsigned long long* __restrict__ keys)
{
    int m = blockIdx.x * 256 + threadIdx.x;
    if (m >= N) return;

    int a  = m % A;
    int hw = m / A;
    int w  = hw % W_;
    int h  = hw / W_;

    float ow = (float)iminfo[1];
    float oh = (float)iminfo[0];

    float aw = c_aw[a], ah = c_ah[a];
    float xm = __fmul_rn(-0.5f, __fsub_rn(aw, 1.0f));
    float ym = __fmul_rn(-0.5f, __fsub_rn(ah, 1.0f));
    float sxw = (float)(w * 8);
    float syh = (float)(h * 8);
    float x1 = __fadd_rn(sxw, xm);
    float y1 = __fadd_rn(syh, ym);
    float x2 = __fadd_rn(sxw, -xm);
    float y2 = __fadd_rn(syh, -ym);

    float widths  = __fadd_rn(__fsub_rn(x2, x1), 1.0f);
    float heights = __fadd_rn(__fsub_rn(y2, y1), 1.0f);
    float ctr_x = __fadd_rn(x1, __fmul_rn(0.5f, __fsub_rn(widths, 1.0f)));
    float ctr_y = __fadd_rn(y1, __fmul_rn(0.5f, __fsub_rn(heights, 1.0f)));

    const float std0 = 0.12677f,   std1 = 0.095741f, std2 = 0.3173f,    std3 = 0.281042f;
    const float mu0  = 0.000437f,  mu1  = 0.002586f, mu2  = -0.123953f, mu3  = -0.081469f;
    int pb = a * 4 * HW + hw;
    float d0 = __fadd_rn(__fmul_rn(pred[pb + 0 * HW], std0), mu0);
    float d1 = __fadd_rn(__fmul_rn(pred[pb + 1 * HW], std1), mu1);
    float d2 = __fadd_rn(__fmul_rn(pred[pb + 2 * HW], std2), mu2);
    float d3 = __fadd_rn(__fmul_rn(pred[pb + 3 * HW], std3), mu3);

    float pcx = __fadd_rn(__fmul_rn(d0, widths),  ctr_x);
    float pcy = __fadd_rn(__fmul_rn(d1, heights), ctr_y);
    float pw  = __fmul_rn(expf(d2), widths);
    float ph  = __fmul_rn(expf(d3), heights);

    float hpw = __fmul_rn(0.5f, __fsub_rn(pw, 1.0f));
    float hph = __fmul_rn(0.5f, __fsub_rn(ph, 1.0f));
    float bx1 = __fsub_rn(pcx, hpw);
    float by1 = __fsub_rn(pcy, hph);
    float bx2 = __fadd_rn(pcx, hpw);
    float by2 = __fadd_rn(pcy, hph);

    float ow1 = __fsub_rn(ow, 1.0f), oh1 = __fsub_rn(oh, 1.0f);
    bx1 = fminf(fmaxf(bx1, 0.0f), ow1);
    by1 = fminf(fmaxf(by1, 0.0f), oh1);
    bx2 = fminf(fmaxf(bx2, 0.0f), ow1);
    by2 = fminf(fmaxf(by2, 0.0f), oh1);

    float s0 = cls[a * HW + hw];
    float s1 = cls[(A + a) * HW + hw];

    float wsv = __fadd_rn(__fsub_rn(bx2, bx1), 1.0f);
    float hsv = __fadd_rn(__fsub_rn(by2, by1), 1.0f);
    bool keep = (s1 > 0.2f) && ((wsv >= 6.16056f) || (hsv >= 6.16056f));
    float masked = keep ? s1 : -1e30f;

    boxes[m]  = make_float4(bx1, by1, bx2, by2);
    scores[m] = make_float2(s0, s1);

    int bucket = keep ? (1 + min(NBUCK - 2, max(0, (int)(s1 * (float)(NBUCK - 2))))) : 0;
    unsigned int fb = __float_as_uint(masked);
    fb = (fb & 0x80000000u) ? ~fb : (fb | 0x80000000u);
    keys[m] = ((unsigned long long)bucket << 51)
            | ((unsigned long long)fb << 15)
            | (unsigned long long)((~m) & 0x7fff);
}

// ---------------------------------------------------------------------------
// K2: single block, 1024 threads. LDS histogram over 8000 buckets ->
// suffix scan -> threshold bucket B of 3000th key -> bucket-grouped compact
// to global skeys -> rank = base[b] + tiny within-bucket compare -> scatter
// cboxes/cscores + kpm bits. Replaces thresh+rank+scatter (no O(S^2)).
// ---------------------------------------------------------------------------
__global__ __launch_bounds__(1024) void k_mid(
    const unsigned long long* __restrict__ keys,
    const float4* __restrict__ boxes, const float2* __restrict__ scores,
    unsigned long long* __restrict__ skeys,
    float4* __restrict__ cboxes, float2* __restrict__ cscores,
    unsigned long long* __restrict__ kpm)
{
    __shared__ int s_base[NBUCK];               // counts -> suffix bases
    __shared__ int s_off[NBUCK];                // tsum alias, then bucket offsets
    __shared__ unsigned long long s_kpm[NWORDS];
    __shared__ int s_B[1];

    const int t = threadIdx.x;

    for (int k = t; k < NBUCK; k += 1024) s_base[k] = 0;
    if (t < NWORDS) s_kpm[t] = 0ull;
    __syncthreads();

    // load 17 keys/thread (coalesced per q); histogram via LDS atomics
    unsigned long long myk[17];
    #pragma unroll
    for (int q = 0; q < 17; ++q) {
        int i = q * 1024 + t;
        myk[q] = (i < N) ? keys[i] : 0ull;
        if (i < N) atomicAdd(&s_base[(int)(myk[q] >> 51)], 1);
    }
    __syncthreads();

    // per-thread group of 8 buckets; block suffix-scan of group sums
    int c0=0,c1=0,c2=0,c3=0,c4=0,c5=0,c6=0,c7=0;
    int gsum = 0;
    const int g0 = t * 8;
    if (t < NBUCK / 8) {
        c0 = s_base[g0+0]; c1 = s_base[g0+1]; c2 = s_base[g0+2]; c3 = s_base[g0+3];
        c4 = s_base[g0+4]; c5 = s_base[g0+5]; c6 = s_base[g0+6]; c7 = s_base[g0+7];
        gsum = c0+c1+c2+c3+c4+c5+c6+c7;
    }
    int* tsum = s_off;
    tsum[t] = gsum;
    __syncthreads();
    for (int d = 1; d < 1024; d <<= 1) {
        int v = (t + d < 1024) ? tsum[t + d] : 0;
        __syncthreads();
        tsum[t] += v;
        __syncthreads();
    }
    int above = (t < 1023) ? tsum[t + 1] : 0;

    // write suffix bases in place; detect threshold bucket B (unique crossing)
    if (t < NBUCK / 8) {
        int run = above;
        #define STEP(q, cq) { s_base[g0+q] = run; \
            if (run < MAX_CAND && run + cq >= MAX_CAND) s_B[0] = g0 + q; \
            run += cq; }
        STEP(7, c7) STEP(6, c6) STEP(5, c5) STEP(4, c4)
        STEP(3, c3) STEP(2, c2) STEP(1, c1) STEP(0, c0)
        #undef STEP
    }
    __syncthreads();
    const int B = s_B[0];
    for (int k = t; k < NBUCK; k += 1024) s_off[k] = 0;
    __syncthreads();

    // compact: bucket-grouped slots (higher buckets first)
    #pragma unroll
    for (int q = 0; q < 17; ++q) {
        int i = q * 1024 + t;
        if (i < N) {
            int b = (int)(myk[q] >> 51);
            if (b >= B) {
                int slot = s_base[b] + atomicAdd(&s_off[b], 1);
                skeys[slot] = myk[q];
            }
        }
    }
    __syncthreads();
    const int S = s_base[B] + s_off[B];

    // rank + scatter (within-bucket compare over ~2 members)
    for (int p = t; p < S; p += 1024) {
        unsigned long long k = skeys[p];
        int b  = (int)(k >> 51);
        int lo = s_base[b];
        int hi = lo + s_off[b];
        int cg = 0;
        for (int j = lo; j < hi; ++j) cg += (skeys[j] > k) ? 1 : 0;
        int rank = lo + cg;
        if (rank < MAX_CAND) {
            int orig = ((int)k & 0x7fff) ^ 0x7fff;
            cboxes[rank]  = boxes[orig];
            cscores[rank] = scores[orig];
            if (b >= 1) atomicOr(&s_kpm[rank >> 6], 1ull << (rank & 63));
        }
    }
    __syncthreads();
    if (t < NWORDS) kpm[t] = s_kpm[t];
}

// ---------------------------------------------------------------------------
// K3: suppression bitmask; 16 i-rows/block, all 3000 boxes staged in LDS.
// bit j of row i set iff iou(i,j)>0.7 && j>i.   (verified R5)
// ---------------------------------------------------------------------------
__global__ __launch_bounds__(256) void k_iou(
    const float4* __restrict__ cboxes, unsigned long long* __restrict__ sup)
{
    __shared__ float4 bx[MAX_CAND];   // 48 KB
    int t = threadIdx.x;
    for (int k = t; k < MAX_CAND; k += 256) bx[k] = cboxes[k];
    __syncthreads();

    int lane = t & 63;
    int wave = t >> 6;
    int i0 = blockIdx.x * ITILE + wave * (ITILE / 4);

    for (int ii = 0; ii < ITILE / 4; ++ii) {
        int i = i0 + ii;
        if (i >= MAX_CAND) continue;
        float4 bi = bx[i];
        float area_i = __fmul_rn(__fsub_rn(bi.z, bi.x), __fsub_rn(bi.w, bi.y));
        for (int w = 0; w < NWORDS; ++w) {
            int j = w * 64 + lane;
            bool p = false;
            if (w * 64 + 63 > i && j < MAX_CAND && j > i) {
                float4 bj = bx[j];
                float iw = fmaxf(__fsub_rn(fminf(bi.z, bj.z), fmaxf(bi.x, bj.x)), 0.0f);
                float ih = fmaxf(__fsub_rn(fminf(bi.w, bj.w), fmaxf(bi.y, bj.y)), 0.0f);
                float inter  = __fmul_rn(iw, ih);
                float area_j = __fmul_rn(__fsub_rn(bj.z, bj.x), __fsub_rn(bj.w, bj.y));
                float denom  = fmaxf(__fsub_rn(__fadd_rn(area_i, area_j), inter), 1e-12f);
                p = (inter / denom) > 0.7f;
            }
            unsigned long long msk = __ballot(p);
            if (lane == 0) sup[(size_t)i * NWORDS + w] = msk;
        }
    }
}

// ---------------------------------------------------------------------------
// K4: chunked greedy NMS over precomputed sup bits; early exit once kept>=300;
// nonzero-row skip; fixed-trip predicated fold; parallel output. (verified R3)
// ---------------------------------------------------------------------------
__global__ __launch_bounds__(1024) void k_nms_out(
    const unsigned long long* __restrict__ sup,
    const unsigned long long* __restrict__ kpm,
    const float4* __restrict__ cboxes, const float2* __restrict__ cscores,
    float* __restrict__ out)
{
    __shared__ unsigned long long buf[2][CHUNK_W];
    __shared__ unsigned long long kp[NWORDS + 1];
    __shared__ int sel[TOP_N];
    __shared__ int s_stop;

    int tid  = threadIdx.x;
    int lane = tid & 63;
    int wave = tid >> 6;

    for (int t = tid; t < TOP_N * 7; t += 1024) out[t] = 0.0f;
    for (int t = tid; t < TOP_N; t += 1024) sel[t] = -1;

    if (tid < NWORDS) kp[tid] = kpm[tid];

    {
        unsigned long long v0 = sup[tid];
        unsigned long long v1 = sup[tid + 1024];
        unsigned long long v2 = (tid + 2048 < CHUNK_W) ? sup[tid + 2048] : 0ull;
        buf[0][tid] = v0;
        buf[0][tid + 1024] = v1;
        if (tid + 2048 < CHUNK_W) buf[0][tid + 2048] = v2;
    }
    __syncthreads();

    int kept_total = 0;
    for (int w = 0; w < NWORDS; ++w) {
        int cur = w & 1;
        bool havnext = (w + 1 < NWORDS);

        unsigned long long v0 = 0, v1 = 0, v2 = 0;
        if (havnext) {
            const unsigned long long* src = sup + (size_t)(w + 1) * CHUNK_W;
            v0 = src[tid];
            v1 = src[tid + 1024];
            v2 = (tid + 2048 < CHUNK_W) ? src[tid + 2048] : 0ull;
        }

        if (wave == 0) {
            unsigned long long intra = buf[cur][lane * NWORDS + w];
            unsigned long long nz = __ballot(intra != 0ull);
            unsigned long long kw = kp[w];
            unsigned long long rem = kw & nz;
            while (rem) {
                int b = __ffsll((long long)rem) - 1;
                rem &= rem - 1;
                if ((kw >> b) & 1ull) {
                    unsigned long long row = __shfl(intra, b, 64);
                    kw  &= ~row;
                    rem &= ~row;
                }
            }
            if (lane == 0) kp[w] = kw;
            kept_total += __popcll(kw);
            bool stop = (kept_total >= TOP_N) || !havnext;
            if (lane == 0) s_stop = stop ? 1 : 0;

            if (!stop && lane < NWORDS && lane > w) {
                unsigned long long comb = 0;
                #pragma unroll 8
                for (int b = 0; b < 64; ++b) {
                    unsigned long long r = buf[cur][b * NWORDS + lane];
                    if ((kw >> b) & 1ull) comb |= r;
                }
                kp[lane] &= ~comb;
            }
        }

        if (havnext) {
            int nxt = cur ^ 1;
            buf[nxt][tid] = v0;
            buf[nxt][tid + 1024] = v1;
            if (tid + 2048 < CHUNK_W) buf[nxt][tid + 2048] = v2;
        }
        __syncthreads();
        if (s_stop) break;
    }

    if (wave == 0) {
        unsigned long long kw = (lane < NWORDS) ? kp[lane] : 0ull;
        int cnt = __popcll(kw);
        int pre = cnt;
        for (int d = 1; d < 64; d <<= 1) {
            int o = __shfl_up(pre, d, 64);
            if (lane >= d) pre += o;
        }
        int prefix = pre - cnt;
        while (kw && prefix < TOP_N) {
            int b = __ffsll((long long)kw) - 1;
            kw &= kw - 1;
            sel[prefix] = lane * 64 + b;
            prefix++;
        }
    }
    __syncthreads();

    if (tid < TOP_N) {
        int j = sel[tid];
        if (j >= 0) {
            float4 bx = cboxes[j];
            float2 sc = cscores[j];
            out[tid * 5 + 0] = 0.0f;
            out[tid * 5 + 1] = bx.x;
            out[tid * 5 + 2] = bx.y;
            out[tid * 5 + 3] = bx.z;
            out[tid * 5 + 4] = bx.w;
            out[TOP_N * 5 + tid * 2 + 0] = sc.x;
            out[TOP_N * 5 + tid * 2 + 1] = sc.y;
        }
    }
}

// ---------------------------------------------------------------------------
extern "C" void kernel_launch(void* const* d_in, const int* in_sizes, int n_in,
                              void* d_out, int out_size, void* d_ws, size_t ws_size,
                              hipStream_t stream) {
    const float* cls    = (const float*)d_in[0];
    const float* pred   = (const float*)d_in[1];
    const int*   iminfo = (const int*)d_in[2];
    float* out = (float*)d_out;

    char* p = (char*)d_ws;
    auto alloc = [&](size_t bytes) -> char* {
        char* q = p;
        p += (bytes + 255) & ~(size_t)255;
        return q;
    };
    float4* boxes  = (float4*)alloc((size_t)N * sizeof(float4));
    float2* scores = (float2*)alloc((size_t)N * sizeof(float2));
    unsigned long long* keys  = (unsigned long long*)alloc((size_t)N * 8);
    unsigned long long* skeys = (unsigned long long*)alloc((size_t)N * 8);
    float4* cboxes  = (float4*)alloc((size_t)MAX_CAND * sizeof(float4));
    float2* cscores = (float2*)alloc((size_t)MAX_CAND * sizeof(float2));
    unsigned long long* kpm = (unsigned long long*)alloc((size_t)NWORDS * 8);
    unsigned long long* sup = (unsigned long long*)alloc((size_t)MAX_CAND * NWORDS * 8);

    int nb = (N + 255) / 256;  // 68
    k_boxes <<<nb, 256, 0, stream>>>(cls, pred, iminfo, boxes, scores, keys);
    k_mid   <<<1, 1024, 0, stream>>>(keys, boxes, scores, skeys, cboxes, cscores, kpm);
    k_iou   <<<(MAX_CAND + ITILE - 1) / ITILE, 256, 0, stream>>>(cboxes, sup);
    k_nms_out<<<1, 1024, 0, stream>>>(sup, kpm, cboxes, cscores, out);
}